// Round 10
// baseline (733.544 us; speedup 1.0000x reference)
//
#include <hip/hip_runtime.h>
#include <hip/hip_cooperative_groups.h>
#include <math.h>

namespace cg = cooperative_groups;

// ---------------------------------------------------------------------------
// TersoffAttention (R9): single cooperative build kernel + fused segment
// kernel (fused unchanged from R8, which passed at absmax 0.0156).
//   R8 profile: fused 85us but TOTAL 267us -> ~183us in the 7-dispatch build
//   chain (memset/init/hist/scan1/scan2/scan3/scatter), none of which shows
//   in top-5 (each < 84us). Estimated real chain work is only ~50-80us, so
//   suspect launch gaps + small-kernel inefficiency. Collapse the chain into
//   ONE hipLaunchCooperativeKernel with grid.sync() phase barriers:
//     P0 rnorm + rowptr=0 | P1 hist (int4) | P2 per-256 scan | P3 bsum scan
//     | P4 add offsets | P5 scatter (int4)
//   Also gives full profiler visibility: only 2 kernels remain.
// ---------------------------------------------------------------------------

#define LOG2E 1.4426950408889634f
#define SCAN_B 256
#define BUILD_BLOCKS 1024
#define BUILD_THREADS 256

__global__ void __launch_bounds__(BUILD_THREADS, 8)
ta_build(const float* __restrict__ r,
         const int* __restrict__ t_dst,
         const int* __restrict__ t_src,
         float4* __restrict__ rnorm4,
         int* __restrict__ rowptr,
         int* __restrict__ bsum,
         int* __restrict__ ssorted,
         int E, int T, int nScanBlocks) {
    cg::grid_group grid = cg::this_grid();
    const int tid = threadIdx.x;
    const int gtid = blockIdx.x * BUILD_THREADS + tid;
    const int nthreads = gridDim.x * BUILD_THREADS;
    __shared__ int sm[512];

    // P0: unit bond directions + zero counters
    for (int i = gtid; i < E; i += nthreads) {
        float rx = r[i * 3 + 0], ry = r[i * 3 + 1], rz = r[i * 3 + 2];
        float inv = rsqrtf(rx * rx + ry * ry + rz * rz);
        rnorm4[i] = make_float4(rx * inv, ry * inv, rz * inv, 0.f);
        rowptr[i] = 0;
    }
    grid.sync();

    // P1: histogram of t_dst (vectorized reads)
    {
        const int T4 = T >> 2;
        const int4* td4 = (const int4*)t_dst;
        for (int i = gtid; i < T4; i += nthreads) {
            int4 d = td4[i];
            atomicAdd(&rowptr[d.x], 1);
            atomicAdd(&rowptr[d.y], 1);
            atomicAdd(&rowptr[d.z], 1);
            atomicAdd(&rowptr[d.w], 1);
        }
        for (int t = (T4 << 2) + gtid; t < T; t += nthreads)
            atomicAdd(&rowptr[t_dst[t]], 1);
    }
    grid.sync();

    // P2: per-256-chunk exclusive scan + chunk totals
    if (blockIdx.x < (unsigned)nScanBlocks) {
        int i = blockIdx.x * SCAN_B + tid;
        int v = (i < E) ? rowptr[i] : 0;
        sm[tid] = v;
        __syncthreads();
        int x = v;
        for (int o = 1; o < SCAN_B; o <<= 1) {
            int y = (tid >= o) ? sm[tid - o] : 0;
            __syncthreads();
            x += y;
            sm[tid] = x;
            __syncthreads();
        }
        if (i < E) rowptr[i] = x - v;
        if (tid == SCAN_B - 1) bsum[blockIdx.x] = x;
    }
    grid.sync();

    // P3: block 0 scans the <=512 chunk totals (2 per thread)
    if (blockIdx.x == 0) {
        int i0 = 2 * tid, i1 = 2 * tid + 1;
        int v0 = (i0 < nScanBlocks) ? bsum[i0] : 0;
        int v1 = (i1 < nScanBlocks) ? bsum[i1] : 0;
        int pair = v0 + v1;
        sm[tid] = pair;
        __syncthreads();
        int x = pair;
        for (int o = 1; o < 256; o <<= 1) {
            int y = (tid >= o) ? sm[tid - o] : 0;
            __syncthreads();
            x += y;
            sm[tid] = x;
            __syncthreads();
        }
        int excl = x - pair;
        if (i0 < nScanBlocks) bsum[i0] = excl;
        if (i1 < nScanBlocks) bsum[i1] = excl + v0;
    }
    grid.sync();

    // P4: add scanned chunk offsets -> rowptr[e] = segment start
    for (int i = gtid; i < E; i += nthreads)
        rowptr[i] += bsum[i >> 8];
    grid.sync();

    // P5: scatter src ids; afterwards rowptr[e] == end-of-segment(e)
    {
        const int T4 = T >> 2;
        const int4* td4 = (const int4*)t_dst;
        const int4* ts4 = (const int4*)t_src;
        for (int i = gtid; i < T4; i += nthreads) {
            int4 d = td4[i];
            int4 s = ts4[i];
            ssorted[atomicAdd(&rowptr[d.x], 1)] = s.x;
            ssorted[atomicAdd(&rowptr[d.y], 1)] = s.y;
            ssorted[atomicAdd(&rowptr[d.z], 1)] = s.z;
            ssorted[atomicAdd(&rowptr[d.w], 1)] = s.w;
        }
        for (int t = (T4 << 2) + gtid; t < T; t += nthreads)
            ssorted[atomicAdd(&rowptr[t_dst[t]], 1)] = t_src[t];
    }
}

// fused: one wave per dst edge e (unchanged from R8).
// Phase A (lane=triplet): acos batch of 64.
// Phase B: 8 groups x 8 lanes, 8 triplets/pass, 8 channels/lane.
__global__ void ta_fused(const float* __restrict__ xij,
                         const float* __restrict__ attn,
                         const float4* __restrict__ rnorm4,
                         const int* __restrict__ ssorted,
                         const int* __restrict__ segend,
                         float* __restrict__ ft, int E) {
    const int lane = threadIdx.x & 63;
    const int waveId = blockIdx.x * (blockDim.x >> 6) + (threadIdx.x >> 6);
    if (waveId >= E) return;
    const int e = waveId;
    const int g   = lane >> 3;          // group 0..7 (triplet slot within pass)
    const int sub = lane & 7;           // lane within group
    const int c0  = sub * 8;            // first channel of this lane's octet
    const float fc0 = (float)c0;

    int end = segend[e];
    int start = (e == 0) ? 0 : segend[e - 1];
    int len = end - start;

    float xd[8], at[8];
    const float* xdp = xij + (size_t)e * 64 + c0;
    *(float4*)&xd[0] = *(const float4*)(xdp);
    *(float4*)&xd[4] = *(const float4*)(xdp + 4);
    *(float4*)&at[0] = *(const float4*)(attn + c0);
    *(float4*)&at[4] = *(const float4*)(attn + c0 + 4);
    const float4 rd = rnorm4[e];

    float m = -3.402823466e38f, den = 0.f;
    float acc[8] = {0, 0, 0, 0, 0, 0, 0, 0};

    for (int chunk = start; chunk < end; chunk += 64) {
        int cl = end - chunk; if (cl > 64) cl = 64;
        // ---- phase A: lane = triplet slot (full-width acos batch) ----
        int idx = chunk + lane; if (idx >= end) idx = end - 1;
        int sv = ssorted[idx];
        float4 rs = rnorm4[sv];
        float cosj = rs.x * rd.x + rs.y * rd.y + rs.z * rd.z;
        cosj = fminf(fmaxf(cosj, -1.0f + 1e-6f), 1.0f - 1e-6f);
        float th2p = acosf(cosj) * 0.15915493667125702f;   // theta/(2pi)

        // ---- phase B: 8 triplets per pass (group g takes triplet j8+g) ----
        for (int j8 = 0; j8 < cl; j8 += 8) {
            int jj = j8 + g;
            bool active = (jj < cl);
            int jc = active ? jj : 0;
            float th = __shfl(th2p, jc, 64);   // theta/(2pi), group-uniform
            float tc = __shfl(cosj, jc, 64);   // cos(theta): Chebyshev mult/2
            int   s  = __shfl(sv,   jc, 64);

            const float* xsp = xij + (size_t)s * 64 + c0;
            float xs[8];
            *(float4*)&xs[0] = *(const float4*)(xsp);
            *(float4*)&xs[4] = *(const float4*)(xsp + 4);

            // Chebyshev seeds: cos(c0*th), cos((c0+1)*th); then recurrence
            float r0 = th * fc0;
            float z0 = __builtin_amdgcn_cosf(r0 - floorf(r0));
            float r1 = r0 + th;
            float z1 = __builtin_amdgcn_cosf(r1 - floorf(r1));
            float twoc = 2.0f * tc;

            float part = 0.f;
            float zkm1 = z0, zk = z1;
            #pragma unroll
            for (int k = 0; k < 8; ++k) {
                float z = (k == 0) ? z0 : zk;
                float v = z + xs[k] + xd[k];
                float ez = __builtin_amdgcn_exp2f(-v * LOG2E);
                float sl = v * __builtin_amdgcn_rcpf(1.0f + ez);   // silu
                part = fmaf(sl, at[k], part);
                if (k > 0) {                       // advance recurrence
                    float zn = fmaf(twoc, zk, -zkm1);
                    zkm1 = zk; zk = zn;
                }
            }
            // dot-reduce within the 8-lane group
            part += __shfl_xor(part, 1, 64);
            part += __shfl_xor(part, 2, 64);
            part += __shfl_xor(part, 4, 64);
            float contrib = active ? part : -3.402823466e38f;
            // per-group online softmax
            float mn = fmaxf(m, contrib);
            float scale = __builtin_amdgcn_exp2f((m - mn) * LOG2E);
            float p     = __builtin_amdgcn_exp2f((contrib - mn) * LOG2E);
            den = den * scale + p;
            #pragma unroll
            for (int k = 0; k < 8; ++k) acc[k] = fmaf(p, xs[k], acc[k] * scale);
            m = mn;
        }
    }

    // merge the 8 groups: required whenever len > 1 (interleaved distribution)
    if (len > 1) {
        #pragma unroll
        for (int off = 8; off < 64; off <<= 1) {
            float m2 = __shfl_xor(m, off, 64);
            float d2 = __shfl_xor(den, off, 64);
            float mn = fmaxf(m, m2);
            float s1 = __builtin_amdgcn_exp2f((m - mn) * LOG2E);
            float s2 = __builtin_amdgcn_exp2f((m2 - mn) * LOG2E);
            den = den * s1 + d2 * s2;
            #pragma unroll
            for (int k = 0; k < 8; ++k) {
                float a2 = __shfl_xor(acc[k], off, 64);
                acc[k] = acc[k] * s1 + a2 * s2;
            }
            m = mn;
        }
    }

    float rden = (len > 0) ? __builtin_amdgcn_rcpf(den) : 0.f;
    if (lane < 8) {                       // lanes 0..7 = group 0, sub = lane
        float out[8];
        #pragma unroll
        for (int k = 0; k < 8; ++k) out[k] = acc[k] * rden;
        float* fo = ft + (size_t)e * 64 + lane * 8;
        *(float4*)(fo)     = *(float4*)&out[0];
        *(float4*)(fo + 4) = *(float4*)&out[4];
    }
}

extern "C" void kernel_launch(void* const* d_in, const int* in_sizes, int n_in,
                              void* d_out, int out_size, void* d_ws, size_t ws_size,
                              hipStream_t stream) {
    const float* xij   = (const float*)d_in[0];
    const float* r     = (const float*)d_in[1];
    const float* attn  = (const float*)d_in[2];
    const int*   t_src = (const int*)d_in[3];
    const int*   t_dst = (const int*)d_in[4];
    float* ft = (float*)d_out;

    int E = in_sizes[1] / 3;   // r is [E,3]
    int T = in_sizes[3];       // t_src is [T]

    // workspace layout (~6 MB for E=100k, T=1M)
    char* ws = (char*)d_ws;
    float4* rnorm4  = (float4*)ws;                                   // E*16 B
    int*    ssorted = (int*)(ws + (size_t)E * 16);                   // T*4 B
    int*    rowptr  = (int*)((char*)ssorted + (size_t)T * 4);        // E*4 B
    int*    bsum    = (int*)((char*)rowptr + (size_t)E * 4);         // <=512*4 B

    int nScanBlocks = (E + SCAN_B - 1) / SCAN_B;   // 391 for E=100k

    const float* r_arg = r;
    const int* td_arg = t_dst;
    const int* ts_arg = t_src;
    void* args[] = {(void*)&r_arg, (void*)&td_arg, (void*)&ts_arg,
                    (void*)&rnorm4, (void*)&rowptr, (void*)&bsum,
                    (void*)&ssorted, (void*)&E, (void*)&T, (void*)&nScanBlocks};
    hipLaunchCooperativeKernel((const void*)ta_build,
                               dim3(BUILD_BLOCKS), dim3(BUILD_THREADS),
                               args, 0, stream);

    ta_fused<<<(E + 3) / 4, 256, 0, stream>>>(xij, attn, rnorm4, ssorted, rowptr, ft, E);
}

// Round 11
// 270.568 us; speedup vs baseline: 2.7111x; 2.7111x over previous
//
#include <hip/hip_runtime.h>
#include <math.h>

// ---------------------------------------------------------------------------
// TersoffAttention (R10): R8 chain, consolidated 8 -> 6 dispatch nodes.
//   R9 lesson: hipLaunchCooperativeKernel grid.sync() costs ~100us/barrier at
//   1024 blocks on gfx950 (ta_build 580us @ VALUBusy 0.17%) -> reverted.
//   R10: (a) init zeroes rowptr (drop memset node), (b) scan3 eliminated by
//   folding chunk offset bsum[.>>8] into scatter's position and fused's
//   segment-bounds reconstruction. Chain: init -> hist -> scan1 -> scan2
//   -> scatter -> fused. ta_fused math unchanged from R8 (85us, passed).
// ---------------------------------------------------------------------------

#define LOG2E 1.4426950408889634f
#define SCAN_B 256

// init: rnorm + zero counters (replaces memset + old init)
__global__ void ta_init(const float* __restrict__ r,
                        float4* __restrict__ rnorm4,
                        int* __restrict__ rowptr,
                        int E) {
    int i = blockIdx.x * blockDim.x + threadIdx.x;
    if (i < E) {
        float rx = r[i * 3 + 0], ry = r[i * 3 + 1], rz = r[i * 3 + 2];
        float inv = rsqrtf(rx * rx + ry * ry + rz * rz);
        rnorm4[i] = make_float4(rx * inv, ry * inv, rz * inv, 0.f);
        rowptr[i] = 0;
    }
}

__global__ void ta_hist(const int* __restrict__ t_dst,
                        int* __restrict__ rowptr, int T) {
    int i = blockIdx.x * blockDim.x + threadIdx.x;
    int T4 = T >> 2;
    if (i < T4) {
        int4 d = ((const int4*)t_dst)[i];
        atomicAdd(&rowptr[d.x], 1);
        atomicAdd(&rowptr[d.y], 1);
        atomicAdd(&rowptr[d.z], 1);
        atomicAdd(&rowptr[d.w], 1);
    }
    int t = (T4 << 2) + i;
    if (i < (T & 3) ? 0 : 0) {}
    if (t < T && i >= T4) {}                       // (tail handled below)
    if (i == 0) {
        for (int u = T4 << 2; u < T; ++u) atomicAdd(&rowptr[t_dst[u]], 1);
    }
}

// scan phase 1: per-256-chunk exclusive scan + chunk totals
__global__ void ta_scan1(int* __restrict__ rowptr, int* __restrict__ bsum, int E) {
    __shared__ int sm[SCAN_B];
    int i = blockIdx.x * SCAN_B + threadIdx.x;
    int v = (i < E) ? rowptr[i] : 0;
    sm[threadIdx.x] = v;
    __syncthreads();
    int x = v;
    for (int o = 1; o < SCAN_B; o <<= 1) {
        int y = (threadIdx.x >= (unsigned)o) ? sm[threadIdx.x - o] : 0;
        __syncthreads();
        x += y;
        sm[threadIdx.x] = x;
        __syncthreads();
    }
    if (i < E) rowptr[i] = x - v;                  // exclusive WITHIN chunk
    if (threadIdx.x == SCAN_B - 1) bsum[blockIdx.x] = x;
}

// scan phase 2: single-block exclusive scan of chunk totals (n <= 512)
__global__ void ta_scan2(int* __restrict__ bsum, int n) {
    __shared__ int sm[512];
    int tid = threadIdx.x;
    int v = (tid < n) ? bsum[tid] : 0;
    sm[tid] = v;
    __syncthreads();
    int x = v;
    for (int o = 1; o < 512; o <<= 1) {
        int y = (tid >= o) ? sm[tid - o] : 0;
        __syncthreads();
        x += y;
        sm[tid] = x;
        __syncthreads();
    }
    if (tid < n) bsum[tid] = x - v;                // exclusive chunk offsets
}

// scatter: global pos = within-chunk atomic pos + chunk offset (kills scan3).
// Afterwards rowptr[e] + bsum[e>>8] == global end-of-segment(e).
__global__ void ta_scatter(const int* __restrict__ t_dst,
                           const int* __restrict__ t_src,
                           int* __restrict__ rowptr,
                           const int* __restrict__ bsum,
                           int* __restrict__ ssorted, int T) {
    int t = blockIdx.x * blockDim.x + threadIdx.x;
    if (t < T) {
        int d = t_dst[t];
        int pos = atomicAdd(&rowptr[d], 1) + bsum[d >> 8];
        ssorted[pos] = t_src[t];
    }
}

// fused: one wave per dst edge e (math identical to R8).
// Phase A (lane=triplet): acos batch of 64.
// Phase B: 8 groups x 8 lanes, 8 triplets/pass, 8 channels/lane.
__global__ void ta_fused(const float* __restrict__ xij,
                         const float* __restrict__ attn,
                         const float4* __restrict__ rnorm4,
                         const int* __restrict__ ssorted,
                         const int* __restrict__ segend,   // rowptr post-scatter
                         const int* __restrict__ bsum,
                         float* __restrict__ ft, int E) {
    const int lane = threadIdx.x & 63;
    const int waveId = blockIdx.x * (blockDim.x >> 6) + (threadIdx.x >> 6);
    if (waveId >= E) return;
    const int e = waveId;
    const int g   = lane >> 3;          // group 0..7 (triplet slot within pass)
    const int sub = lane & 7;           // lane within group
    const int c0  = sub * 8;            // first channel of this lane's octet
    const float fc0 = (float)c0;

    int end = segend[e] + bsum[e >> 8];
    int start = (e == 0) ? 0 : (segend[e - 1] + bsum[(e - 1) >> 8]);
    int len = end - start;

    float xd[8], at[8];
    const float* xdp = xij + (size_t)e * 64 + c0;
    *(float4*)&xd[0] = *(const float4*)(xdp);
    *(float4*)&xd[4] = *(const float4*)(xdp + 4);
    *(float4*)&at[0] = *(const float4*)(attn + c0);
    *(float4*)&at[4] = *(const float4*)(attn + c0 + 4);
    const float4 rd = rnorm4[e];

    float m = -3.402823466e38f, den = 0.f;
    float acc[8] = {0, 0, 0, 0, 0, 0, 0, 0};

    for (int chunk = start; chunk < end; chunk += 64) {
        int cl = end - chunk; if (cl > 64) cl = 64;
        // ---- phase A: lane = triplet slot (full-width acos batch) ----
        int idx = chunk + lane; if (idx >= end) idx = end - 1;
        int sv = ssorted[idx];
        float4 rs = rnorm4[sv];
        float cosj = rs.x * rd.x + rs.y * rd.y + rs.z * rd.z;
        cosj = fminf(fmaxf(cosj, -1.0f + 1e-6f), 1.0f - 1e-6f);
        float th2p = acosf(cosj) * 0.15915493667125702f;   // theta/(2pi)

        // ---- phase B: 8 triplets per pass (group g takes triplet j8+g) ----
        for (int j8 = 0; j8 < cl; j8 += 8) {
            int jj = j8 + g;
            bool active = (jj < cl);
            int jc = active ? jj : 0;
            float th = __shfl(th2p, jc, 64);   // theta/(2pi), group-uniform
            float tc = __shfl(cosj, jc, 64);   // cos(theta): Chebyshev mult/2
            int   s  = __shfl(sv,   jc, 64);

            const float* xsp = xij + (size_t)s * 64 + c0;
            float xs[8];
            *(float4*)&xs[0] = *(const float4*)(xsp);
            *(float4*)&xs[4] = *(const float4*)(xsp + 4);

            // Chebyshev seeds: cos(c0*th), cos((c0+1)*th); then recurrence
            float r0 = th * fc0;
            float z0 = __builtin_amdgcn_cosf(r0 - floorf(r0));
            float r1 = r0 + th;
            float z1 = __builtin_amdgcn_cosf(r1 - floorf(r1));
            float twoc = 2.0f * tc;

            float part = 0.f;
            float zkm1 = z0, zk = z1;
            #pragma unroll
            for (int k = 0; k < 8; ++k) {
                float z = (k == 0) ? z0 : zk;
                float v = z + xs[k] + xd[k];
                float ez = __builtin_amdgcn_exp2f(-v * LOG2E);
                float sl = v * __builtin_amdgcn_rcpf(1.0f + ez);   // silu
                part = fmaf(sl, at[k], part);
                if (k > 0) {                       // advance recurrence
                    float zn = fmaf(twoc, zk, -zkm1);
                    zkm1 = zk; zk = zn;
                }
            }
            // dot-reduce within the 8-lane group
            part += __shfl_xor(part, 1, 64);
            part += __shfl_xor(part, 2, 64);
            part += __shfl_xor(part, 4, 64);
            float contrib = active ? part : -3.402823466e38f;
            // per-group online softmax
            float mn = fmaxf(m, contrib);
            float scale = __builtin_amdgcn_exp2f((m - mn) * LOG2E);
            float p     = __builtin_amdgcn_exp2f((contrib - mn) * LOG2E);
            den = den * scale + p;
            #pragma unroll
            for (int k = 0; k < 8; ++k) acc[k] = fmaf(p, xs[k], acc[k] * scale);
            m = mn;
        }
    }

    // merge the 8 groups: required whenever len > 1 (interleaved distribution)
    if (len > 1) {
        #pragma unroll
        for (int off = 8; off < 64; off <<= 1) {
            float m2 = __shfl_xor(m, off, 64);
            float d2 = __shfl_xor(den, off, 64);
            float mn = fmaxf(m, m2);
            float s1 = __builtin_amdgcn_exp2f((m - mn) * LOG2E);
            float s2 = __builtin_amdgcn_exp2f((m2 - mn) * LOG2E);
            den = den * s1 + d2 * s2;
            #pragma unroll
            for (int k = 0; k < 8; ++k) {
                float a2 = __shfl_xor(acc[k], off, 64);
                acc[k] = acc[k] * s1 + a2 * s2;
            }
            m = mn;
        }
    }

    float rden = (len > 0) ? __builtin_amdgcn_rcpf(den) : 0.f;
    if (lane < 8) {                       // lanes 0..7 = group 0, sub = lane
        float out[8];
        #pragma unroll
        for (int k = 0; k < 8; ++k) out[k] = acc[k] * rden;
        float* fo = ft + (size_t)e * 64 + lane * 8;
        *(float4*)(fo)     = *(float4*)&out[0];
        *(float4*)(fo + 4) = *(float4*)&out[4];
    }
}

extern "C" void kernel_launch(void* const* d_in, const int* in_sizes, int n_in,
                              void* d_out, int out_size, void* d_ws, size_t ws_size,
                              hipStream_t stream) {
    const float* xij   = (const float*)d_in[0];
    const float* r     = (const float*)d_in[1];
    const float* attn  = (const float*)d_in[2];
    const int*   t_src = (const int*)d_in[3];
    const int*   t_dst = (const int*)d_in[4];
    float* ft = (float*)d_out;

    const int E = in_sizes[1] / 3;   // r is [E,3]
    const int T = in_sizes[3];       // t_src is [T]

    // workspace layout (~6 MB for E=100k, T=1M)
    char* ws = (char*)d_ws;
    float4* rnorm4  = (float4*)ws;                                   // E*16 B
    int*    ssorted = (int*)(ws + (size_t)E * 16);                   // T*4 B
    int*    rowptr  = (int*)((char*)ssorted + (size_t)T * 4);        // E*4 B
    int*    bsum    = (int*)((char*)rowptr + (size_t)E * 4);         // <=512*4 B

    const int nScanBlocks = (E + SCAN_B - 1) / SCAN_B;   // 391 for E=100k

    ta_init<<<(E + 255) / 256, 256, 0, stream>>>(r, rnorm4, rowptr, E);
    ta_hist<<<((T >> 2) + 255) / 256, 256, 0, stream>>>(t_dst, rowptr, T);
    ta_scan1<<<nScanBlocks, SCAN_B, 0, stream>>>(rowptr, bsum, E);
    ta_scan2<<<1, 512, 0, stream>>>(bsum, nScanBlocks);
    ta_scatter<<<(T + 255) / 256, 256, 0, stream>>>(t_dst, t_src, rowptr, bsum, ssorted, T);
    ta_fused<<<(E + 3) / 4, 256, 0, stream>>>(xij, attn, rnorm4, ssorted, rowptr, bsum, ft, E);
}

// Round 12
// 219.510 us; speedup vs baseline: 3.3417x; 1.2326x over previous
//
#include <hip/hip_runtime.h>
#include <math.h>

// ---------------------------------------------------------------------------
// TersoffAttention (R11): direct bucket scatter — hist & scan deleted.
//   R10 null result: removing 2 launch nodes changed nothing -> chain cost is
//   real work (2M random memory-side atomics in hist+scatter). New structure:
//   per-edge fixed-capacity buckets (CAP=32; P(Poisson(10)>32)~4e-9), scatter
//   does ONE atomicAdd per triplet and writes src into bucket[d*CAP+pos].
//   Overflow -> tiny spill list, consumed by a (never-taken) slow path in
//   fused. If ws_size can't fit buckets, fall back to the proven R10 chain.
//   Chain: init -> scatter. ta_fused math identical to R10 (86us, passed).
// ---------------------------------------------------------------------------

#define LOG2E 1.4426950408889634f
#define SCAN_B 256
#define SPILL_PAIRS 65536

// ===================== bucket path =====================

__global__ void ta_init_b(const float* __restrict__ r,
                          float4* __restrict__ rnorm4,
                          int* __restrict__ cnt,
                          int* __restrict__ spill_cnt,
                          int E) {
    int i = blockIdx.x * blockDim.x + threadIdx.x;
    if (i < E) {
        float rx = r[i * 3 + 0], ry = r[i * 3 + 1], rz = r[i * 3 + 2];
        float inv = rsqrtf(rx * rx + ry * ry + rz * rz);
        rnorm4[i] = make_float4(rx * inv, ry * inv, rz * inv, 0.f);
        cnt[i] = 0;
    }
    if (i == 0) *spill_cnt = 0;
}

__global__ void ta_scatter_b(const int* __restrict__ t_dst,
                             const int* __restrict__ t_src,
                             int* __restrict__ cnt,
                             int* __restrict__ bucket,
                             int* __restrict__ spill,      // pairs (d, src)
                             int* __restrict__ spill_cnt,
                             int T, int CAP) {
    int i = blockIdx.x * blockDim.x + threadIdx.x;
    int T4 = T >> 2;
    if (i < T4) {
        int4 d = ((const int4*)t_dst)[i];
        int4 s = ((const int4*)t_src)[i];
        int p0 = atomicAdd(&cnt[d.x], 1);
        int p1 = atomicAdd(&cnt[d.y], 1);
        int p2 = atomicAdd(&cnt[d.z], 1);
        int p3 = atomicAdd(&cnt[d.w], 1);
        if (p0 < CAP) bucket[(size_t)d.x * CAP + p0] = s.x;
        else { int u = atomicAdd(spill_cnt, 1); if (u < SPILL_PAIRS) { spill[2*u] = d.x; spill[2*u+1] = s.x; } }
        if (p1 < CAP) bucket[(size_t)d.y * CAP + p1] = s.y;
        else { int u = atomicAdd(spill_cnt, 1); if (u < SPILL_PAIRS) { spill[2*u] = d.y; spill[2*u+1] = s.y; } }
        if (p2 < CAP) bucket[(size_t)d.z * CAP + p2] = s.z;
        else { int u = atomicAdd(spill_cnt, 1); if (u < SPILL_PAIRS) { spill[2*u] = d.z; spill[2*u+1] = s.z; } }
        if (p3 < CAP) bucket[(size_t)d.w * CAP + p3] = s.w;
        else { int u = atomicAdd(spill_cnt, 1); if (u < SPILL_PAIRS) { spill[2*u] = d.w; spill[2*u+1] = s.w; } }
    }
    if (i == 0) {                       // generic tail (T%4 != 0)
        for (int t = T4 << 2; t < T; ++t) {
            int d = t_dst[t];
            int p = atomicAdd(&cnt[d], 1);
            if (p < CAP) bucket[(size_t)d * CAP + p] = t_src[t];
            else { int u = atomicAdd(spill_cnt, 1); if (u < SPILL_PAIRS) { spill[2*u] = d; spill[2*u+1] = t_src[t]; } }
        }
    }
}

// fused: one wave per dst edge e. Phase A (lane=triplet): acos batch.
// Phase B: 8 groups x 8 lanes, 8 triplets/pass, 8 channels/lane.
__global__ void ta_fused_b(const float* __restrict__ xij,
                           const float* __restrict__ attn,
                           const float4* __restrict__ rnorm4,
                           const int* __restrict__ bucket,
                           const int* __restrict__ cnt,
                           const int* __restrict__ spill,
                           const int* __restrict__ spill_cnt,
                           float* __restrict__ ft, int E, int CAP) {
    const int lane = threadIdx.x & 63;
    const int waveId = blockIdx.x * (blockDim.x >> 6) + (threadIdx.x >> 6);
    if (waveId >= E) return;
    const int e = waveId;
    const int g   = lane >> 3;          // group (triplet slot within pass)
    const int sub = lane & 7;           // lane within group
    const int c0  = sub * 8;            // first channel of this lane's octet
    const float fc0 = (float)c0;

    int len = cnt[e];
    int eff = (len < CAP) ? len : CAP;  // in-bucket count
    const int* bkt = bucket + (size_t)e * CAP;

    float xd[8], at[8];
    const float* xdp = xij + (size_t)e * 64 + c0;
    *(float4*)&xd[0] = *(const float4*)(xdp);
    *(float4*)&xd[4] = *(const float4*)(xdp + 4);
    *(float4*)&at[0] = *(const float4*)(attn + c0);
    *(float4*)&at[4] = *(const float4*)(attn + c0 + 4);
    const float4 rd = rnorm4[e];

    float m = -3.402823466e38f, den = 0.f;
    float acc[8] = {0, 0, 0, 0, 0, 0, 0, 0};

    for (int chunk = 0; chunk < eff; chunk += 64) {
        int cl = eff - chunk; if (cl > 64) cl = 64;
        // ---- phase A: lane = triplet slot ----
        int idx = chunk + lane; if (idx >= eff) idx = eff - 1;
        int sv = bkt[idx];
        float4 rs = rnorm4[sv];
        float cosj = rs.x * rd.x + rs.y * rd.y + rs.z * rd.z;
        cosj = fminf(fmaxf(cosj, -1.0f + 1e-6f), 1.0f - 1e-6f);
        float th2p = acosf(cosj) * 0.15915493667125702f;   // theta/(2pi)

        // ---- phase B: 8 triplets per pass (group g takes triplet j8+g) ----
        for (int j8 = 0; j8 < cl; j8 += 8) {
            int jj = j8 + g;
            bool active = (jj < cl);
            int jc = active ? jj : 0;
            float th = __shfl(th2p, jc, 64);
            float tc = __shfl(cosj, jc, 64);   // cos(theta): Chebyshev mult/2
            int   s  = __shfl(sv,   jc, 64);

            const float* xsp = xij + (size_t)s * 64 + c0;
            float xs[8];
            *(float4*)&xs[0] = *(const float4*)(xsp);
            *(float4*)&xs[4] = *(const float4*)(xsp + 4);

            float r0 = th * fc0;
            float z0 = __builtin_amdgcn_cosf(r0 - floorf(r0));
            float r1 = r0 + th;
            float z1 = __builtin_amdgcn_cosf(r1 - floorf(r1));
            float twoc = 2.0f * tc;

            float part = 0.f;
            float zkm1 = z0, zk = z1;
            #pragma unroll
            for (int k = 0; k < 8; ++k) {
                float z = (k == 0) ? z0 : zk;
                float v = z + xs[k] + xd[k];
                float ez = __builtin_amdgcn_exp2f(-v * LOG2E);
                float sl = v * __builtin_amdgcn_rcpf(1.0f + ez);   // silu
                part = fmaf(sl, at[k], part);
                if (k > 0) {
                    float zn = fmaf(twoc, zk, -zkm1);
                    zkm1 = zk; zk = zn;
                }
            }
            part += __shfl_xor(part, 1, 64);
            part += __shfl_xor(part, 2, 64);
            part += __shfl_xor(part, 4, 64);
            float contrib = active ? part : -3.402823466e38f;
            float mn = fmaxf(m, contrib);
            float scale = __builtin_amdgcn_exp2f((m - mn) * LOG2E);
            float p     = __builtin_amdgcn_exp2f((contrib - mn) * LOG2E);
            den = den * scale + p;
            #pragma unroll
            for (int k = 0; k < 8; ++k) acc[k] = fmaf(p, xs[k], acc[k] * scale);
            m = mn;
        }
    }

    // overflow slow path (never taken for CAP=32 on this data)
    if (len > CAP) {
        int ns = *spill_cnt; if (ns > SPILL_PAIRS) ns = SPILL_PAIRS;
        for (int u = 0; u < ns; ++u) {
            int d2 = spill[2 * u];
            if (d2 != e) continue;
            int s2 = spill[2 * u + 1];
            float4 rs = rnorm4[s2];
            float cosj = rs.x * rd.x + rs.y * rd.y + rs.z * rd.z;
            cosj = fminf(fmaxf(cosj, -1.0f + 1e-6f), 1.0f - 1e-6f);
            float th = acosf(cosj) * 0.15915493667125702f;
            const float* xsp = xij + (size_t)s2 * 64 + c0;
            float xs[8];
            *(float4*)&xs[0] = *(const float4*)(xsp);
            *(float4*)&xs[4] = *(const float4*)(xsp + 4);
            float r0 = th * fc0;
            float z0 = __builtin_amdgcn_cosf(r0 - floorf(r0));
            float r1 = r0 + th;
            float z1 = __builtin_amdgcn_cosf(r1 - floorf(r1));
            float twoc = 2.0f * cosj;
            float part = 0.f;
            float zkm1 = z0, zk = z1;
            #pragma unroll
            for (int k = 0; k < 8; ++k) {
                float z = (k == 0) ? z0 : zk;
                float v = z + xs[k] + xd[k];
                float ez = __builtin_amdgcn_exp2f(-v * LOG2E);
                float sl = v * __builtin_amdgcn_rcpf(1.0f + ez);
                part = fmaf(sl, at[k], part);
                if (k > 0) { float zn = fmaf(twoc, zk, -zkm1); zkm1 = zk; zk = zn; }
            }
            part += __shfl_xor(part, 1, 64);
            part += __shfl_xor(part, 2, 64);
            part += __shfl_xor(part, 4, 64);   // full 64-dot in every group
            if (g == 0) {                      // update group 0's state once
                float mn = fmaxf(m, part);
                float scale = __builtin_amdgcn_exp2f((m - mn) * LOG2E);
                float p     = __builtin_amdgcn_exp2f((part - mn) * LOG2E);
                den = den * scale + p;
                #pragma unroll
                for (int k = 0; k < 8; ++k) acc[k] = fmaf(p, xs[k], acc[k] * scale);
                m = mn;
            }
        }
    }

    if (len > 1) {                             // merge the 8 groups
        #pragma unroll
        for (int off = 8; off < 64; off <<= 1) {
            float m2 = __shfl_xor(m, off, 64);
            float d2 = __shfl_xor(den, off, 64);
            float mn = fmaxf(m, m2);
            float s1 = __builtin_amdgcn_exp2f((m - mn) * LOG2E);
            float s2 = __builtin_amdgcn_exp2f((m2 - mn) * LOG2E);
            den = den * s1 + d2 * s2;
            #pragma unroll
            for (int k = 0; k < 8; ++k) {
                float a2 = __shfl_xor(acc[k], off, 64);
                acc[k] = acc[k] * s1 + a2 * s2;
            }
            m = mn;
        }
    }

    float rden = (len > 0) ? __builtin_amdgcn_rcpf(den) : 0.f;
    if (lane < 8) {
        float out[8];
        #pragma unroll
        for (int k = 0; k < 8; ++k) out[k] = acc[k] * rden;
        float* fo = ft + (size_t)e * 64 + lane * 8;
        *(float4*)(fo)     = *(float4*)&out[0];
        *(float4*)(fo + 4) = *(float4*)&out[4];
    }
}

// ===================== R10 fallback path (proven) =====================

__global__ void ta_init(const float* __restrict__ r, float4* __restrict__ rnorm4,
                        int* __restrict__ rowptr, int E) {
    int i = blockIdx.x * blockDim.x + threadIdx.x;
    if (i < E) {
        float rx = r[i * 3 + 0], ry = r[i * 3 + 1], rz = r[i * 3 + 2];
        float inv = rsqrtf(rx * rx + ry * ry + rz * rz);
        rnorm4[i] = make_float4(rx * inv, ry * inv, rz * inv, 0.f);
        rowptr[i] = 0;
    }
}

__global__ void ta_hist(const int* __restrict__ t_dst, int* __restrict__ rowptr, int T) {
    int i = blockIdx.x * blockDim.x + threadIdx.x;
    int T4 = T >> 2;
    if (i < T4) {
        int4 d = ((const int4*)t_dst)[i];
        atomicAdd(&rowptr[d.x], 1);
        atomicAdd(&rowptr[d.y], 1);
        atomicAdd(&rowptr[d.z], 1);
        atomicAdd(&rowptr[d.w], 1);
    }
    if (i == 0) for (int u = T4 << 2; u < T; ++u) atomicAdd(&rowptr[t_dst[u]], 1);
}

__global__ void ta_scan1(int* __restrict__ rowptr, int* __restrict__ bsum, int E) {
    __shared__ int sm[SCAN_B];
    int i = blockIdx.x * SCAN_B + threadIdx.x;
    int v = (i < E) ? rowptr[i] : 0;
    sm[threadIdx.x] = v;
    __syncthreads();
    int x = v;
    for (int o = 1; o < SCAN_B; o <<= 1) {
        int y = (threadIdx.x >= (unsigned)o) ? sm[threadIdx.x - o] : 0;
        __syncthreads();
        x += y; sm[threadIdx.x] = x;
        __syncthreads();
    }
    if (i < E) rowptr[i] = x - v;
    if (threadIdx.x == SCAN_B - 1) bsum[blockIdx.x] = x;
}

__global__ void ta_scan2(int* __restrict__ bsum, int n) {
    __shared__ int sm[512];
    int tid = threadIdx.x;
    int v = (tid < n) ? bsum[tid] : 0;
    sm[tid] = v;
    __syncthreads();
    int x = v;
    for (int o = 1; o < 512; o <<= 1) {
        int y = (tid >= o) ? sm[tid - o] : 0;
        __syncthreads();
        x += y; sm[tid] = x;
        __syncthreads();
    }
    if (tid < n) bsum[tid] = x - v;
}

__global__ void ta_scatter(const int* __restrict__ t_dst, const int* __restrict__ t_src,
                           int* __restrict__ rowptr, const int* __restrict__ bsum,
                           int* __restrict__ ssorted, int T) {
    int t = blockIdx.x * blockDim.x + threadIdx.x;
    if (t < T) {
        int d = t_dst[t];
        int pos = atomicAdd(&rowptr[d], 1) + bsum[d >> 8];
        ssorted[pos] = t_src[t];
    }
}

__global__ void ta_fused(const float* __restrict__ xij, const float* __restrict__ attn,
                         const float4* __restrict__ rnorm4, const int* __restrict__ ssorted,
                         const int* __restrict__ segend, const int* __restrict__ bsum,
                         float* __restrict__ ft, int E) {
    const int lane = threadIdx.x & 63;
    const int waveId = blockIdx.x * (blockDim.x >> 6) + (threadIdx.x >> 6);
    if (waveId >= E) return;
    const int e = waveId;
    const int g = lane >> 3, sub = lane & 7, c0 = sub * 8;
    const float fc0 = (float)c0;
    int end = segend[e] + bsum[e >> 8];
    int start = (e == 0) ? 0 : (segend[e - 1] + bsum[(e - 1) >> 8]);
    int len = end - start;
    float xd[8], at[8];
    const float* xdp = xij + (size_t)e * 64 + c0;
    *(float4*)&xd[0] = *(const float4*)(xdp);
    *(float4*)&xd[4] = *(const float4*)(xdp + 4);
    *(float4*)&at[0] = *(const float4*)(attn + c0);
    *(float4*)&at[4] = *(const float4*)(attn + c0 + 4);
    const float4 rd = rnorm4[e];
    float m = -3.402823466e38f, den = 0.f;
    float acc[8] = {0, 0, 0, 0, 0, 0, 0, 0};
    for (int chunk = start; chunk < end; chunk += 64) {
        int cl = end - chunk; if (cl > 64) cl = 64;
        int idx = chunk + lane; if (idx >= end) idx = end - 1;
        int sv = ssorted[idx];
        float4 rs = rnorm4[sv];
        float cosj = rs.x * rd.x + rs.y * rd.y + rs.z * rd.z;
        cosj = fminf(fmaxf(cosj, -1.0f + 1e-6f), 1.0f - 1e-6f);
        float th2p = acosf(cosj) * 0.15915493667125702f;
        for (int j8 = 0; j8 < cl; j8 += 8) {
            int jj = j8 + g;
            bool active = (jj < cl);
            int jc = active ? jj : 0;
            float th = __shfl(th2p, jc, 64);
            float tc = __shfl(cosj, jc, 64);
            int   s  = __shfl(sv,   jc, 64);
            const float* xsp = xij + (size_t)s * 64 + c0;
            float xs[8];
            *(float4*)&xs[0] = *(const float4*)(xsp);
            *(float4*)&xs[4] = *(const float4*)(xsp + 4);
            float r0 = th * fc0;
            float z0 = __builtin_amdgcn_cosf(r0 - floorf(r0));
            float r1 = r0 + th;
            float z1 = __builtin_amdgcn_cosf(r1 - floorf(r1));
            float twoc = 2.0f * tc;
            float part = 0.f;
            float zkm1 = z0, zk = z1;
            #pragma unroll
            for (int k = 0; k < 8; ++k) {
                float z = (k == 0) ? z0 : zk;
                float v = z + xs[k] + xd[k];
                float ez = __builtin_amdgcn_exp2f(-v * LOG2E);
                float sl = v * __builtin_amdgcn_rcpf(1.0f + ez);
                part = fmaf(sl, at[k], part);
                if (k > 0) { float zn = fmaf(twoc, zk, -zkm1); zkm1 = zk; zk = zn; }
            }
            part += __shfl_xor(part, 1, 64);
            part += __shfl_xor(part, 2, 64);
            part += __shfl_xor(part, 4, 64);
            float contrib = active ? part : -3.402823466e38f;
            float mn = fmaxf(m, contrib);
            float scale = __builtin_amdgcn_exp2f((m - mn) * LOG2E);
            float p     = __builtin_amdgcn_exp2f((contrib - mn) * LOG2E);
            den = den * scale + p;
            #pragma unroll
            for (int k = 0; k < 8; ++k) acc[k] = fmaf(p, xs[k], acc[k] * scale);
            m = mn;
        }
    }
    if (len > 1) {
        #pragma unroll
        for (int off = 8; off < 64; off <<= 1) {
            float m2 = __shfl_xor(m, off, 64);
            float d2 = __shfl_xor(den, off, 64);
            float mn = fmaxf(m, m2);
            float s1 = __builtin_amdgcn_exp2f((m - mn) * LOG2E);
            float s2 = __builtin_amdgcn_exp2f((m2 - mn) * LOG2E);
            den = den * s1 + d2 * s2;
            #pragma unroll
            for (int k = 0; k < 8; ++k) {
                float a2 = __shfl_xor(acc[k], off, 64);
                acc[k] = acc[k] * s1 + a2 * s2;
            }
            m = mn;
        }
    }
    float rden = (len > 0) ? __builtin_amdgcn_rcpf(den) : 0.f;
    if (lane < 8) {
        float out[8];
        #pragma unroll
        for (int k = 0; k < 8; ++k) out[k] = acc[k] * rden;
        float* fo = ft + (size_t)e * 64 + lane * 8;
        *(float4*)(fo)     = *(float4*)&out[0];
        *(float4*)(fo + 4) = *(float4*)&out[4];
    }
}

// ===================== launch =====================

extern "C" void kernel_launch(void* const* d_in, const int* in_sizes, int n_in,
                              void* d_out, int out_size, void* d_ws, size_t ws_size,
                              hipStream_t stream) {
    const float* xij   = (const float*)d_in[0];
    const float* r     = (const float*)d_in[1];
    const float* attn  = (const float*)d_in[2];
    const int*   t_src = (const int*)d_in[3];
    const int*   t_dst = (const int*)d_in[4];
    float* ft = (float*)d_out;

    const int E = in_sizes[1] / 3;   // r is [E,3]
    const int T = in_sizes[3];       // t_src is [T]

    // choose bucket capacity that fits ws
    size_t fixed = (size_t)E * 16 + (size_t)E * 4 + 4 + (size_t)SPILL_PAIRS * 8;
    int CAP = 0;
    if (fixed + (size_t)E * 32 * 4 <= ws_size) CAP = 32;
    else if (fixed + (size_t)E * 24 * 4 <= ws_size) CAP = 24;
    else if (fixed + (size_t)E * 16 * 4 <= ws_size) CAP = 16;

    char* ws = (char*)d_ws;
    if (CAP >= 16) {
        // bucket path: rnorm4 | cnt | spill_cnt | spill | bucket
        float4* rnorm4    = (float4*)ws;
        int*    cnt       = (int*)(ws + (size_t)E * 16);
        int*    spill_cnt = (int*)((char*)cnt + (size_t)E * 4);
        int*    spill     = spill_cnt + 1;
        int*    bucket    = spill + (size_t)SPILL_PAIRS * 2;

        ta_init_b<<<(E + 255) / 256, 256, 0, stream>>>(r, rnorm4, cnt, spill_cnt, E);
        ta_scatter_b<<<((T >> 2) + 255) / 256, 256, 0, stream>>>(
            t_dst, t_src, cnt, bucket, spill, spill_cnt, T, CAP);
        ta_fused_b<<<(E + 3) / 4, 256, 0, stream>>>(
            xij, attn, rnorm4, bucket, cnt, spill, spill_cnt, ft, E, CAP);
    } else {
        // R10 fallback: rnorm4 | ssorted | rowptr | bsum
        float4* rnorm4  = (float4*)ws;
        int*    ssorted = (int*)(ws + (size_t)E * 16);
        int*    rowptr  = (int*)((char*)ssorted + (size_t)T * 4);
        int*    bsum    = (int*)((char*)rowptr + (size_t)E * 4);
        const int nScanBlocks = (E + SCAN_B - 1) / SCAN_B;

        ta_init<<<(E + 255) / 256, 256, 0, stream>>>(r, rnorm4, rowptr, E);
        ta_hist<<<((T >> 2) + 255) / 256, 256, 0, stream>>>(t_dst, rowptr, T);
        ta_scan1<<<nScanBlocks, SCAN_B, 0, stream>>>(rowptr, bsum, E);
        ta_scan2<<<1, 512, 0, stream>>>(bsum, nScanBlocks);
        ta_scatter<<<(T + 255) / 256, 256, 0, stream>>>(t_dst, t_src, rowptr, bsum, ssorted, T);
        ta_fused<<<(E + 3) / 4, 256, 0, stream>>>(xij, attn, rnorm4, ssorted, rowptr, bsum, ft, E);
    }
}